// Round 6
// baseline (347.449 us; speedup 1.0000x reference)
//
#include <hip/hip_runtime.h>
#include <stdint.h>

typedef int   i32x8 __attribute__((ext_vector_type(8)));
typedef float f32x4 __attribute__((ext_vector_type(4)));

#define B_ROWS 8192
#define D_DIM  512
#define GRID_SIMMIN 4096

// monotone float<->uint encoding: enc order == float order (uint atomicMin
// == float min). f>=0: set sign bit; f<0: bitwise NOT.
__device__ __forceinline__ uint32_t enc_f32(float f) {
  uint32_t s = __float_as_uint(f);
  return (s & 0x80000000u) ? ~s : (s | 0x80000000u);
}
__device__ __forceinline__ float dec_f32(uint32_t e) {
  uint32_t s = (e & 0x80000000u) ? (e ^ 0x80000000u) : ~e;
  return __uint_as_float(s);
}

// ---------------------------------------------------------------------------
// Kernel 1: per-row normalize (fp32 -> fp8 e4m3) + cos(anchor, positive).
// Wave per row. Inits minenc[r]=+inf-enc and zeroes the done-counter.
// ---------------------------------------------------------------------------
__global__ __launch_bounds__(256) void norm_kernel(
    const float* __restrict__ anchor, const float* __restrict__ positive,
    uint32_t* __restrict__ a8, uint32_t* __restrict__ p8,
    float* __restrict__ cos_ap, uint32_t* __restrict__ minenc,
    uint32_t* __restrict__ donecnt)
{
  const int wave = threadIdx.x >> 6, lane = threadIdx.x & 63;
  const int r = blockIdx.x * 4 + wave;

  const float4* av = (const float4*)(anchor   + (size_t)r * D_DIM) + lane * 2;
  const float4* pv = (const float4*)(positive + (size_t)r * D_DIM) + lane * 2;
  float4 a0 = av[0], a1 = av[1];
  float4 p0 = pv[0], p1 = pv[1];

  float sa = a0.x*a0.x + a0.y*a0.y + a0.z*a0.z + a0.w*a0.w
           + a1.x*a1.x + a1.y*a1.y + a1.z*a1.z + a1.w*a1.w;
  float sp = p0.x*p0.x + p0.y*p0.y + p0.z*p0.z + p0.w*p0.w
           + p1.x*p1.x + p1.y*p1.y + p1.z*p1.z + p1.w*p1.w;
  float dp = a0.x*p0.x + a0.y*p0.y + a0.z*p0.z + a0.w*p0.w
           + a1.x*p1.x + a1.y*p1.y + a1.z*p1.z + a1.w*p1.w;

#pragma unroll
  for (int d = 1; d < 64; d <<= 1) {
    sa += __shfl_xor(sa, d);
    sp += __shfl_xor(sp, d);
    dp += __shfl_xor(dp, d);
  }

  const float na = sqrtf(sa), np = sqrtf(sp);
  const float ia = 1.0f / na, ip = 1.0f / np;

  float na0 = a0.x*ia, na1 = a0.y*ia, na2 = a0.z*ia, na3 = a0.w*ia;
  float na4 = a1.x*ia, na5 = a1.y*ia, na6 = a1.z*ia, na7 = a1.w*ia;
  float np0 = p0.x*ip, np1 = p0.y*ip, np2 = p0.z*ip, np3 = p0.w*ip;
  float np4 = p1.x*ip, np5 = p1.y*ip, np6 = p1.z*ip, np7 = p1.w*ip;

  uint32_t aw0 = __builtin_amdgcn_cvt_pk_fp8_f32(na0, na1, 0,  false);
  aw0          = __builtin_amdgcn_cvt_pk_fp8_f32(na2, na3, aw0, true);
  uint32_t aw1 = __builtin_amdgcn_cvt_pk_fp8_f32(na4, na5, 0,  false);
  aw1          = __builtin_amdgcn_cvt_pk_fp8_f32(na6, na7, aw1, true);
  uint32_t pw0 = __builtin_amdgcn_cvt_pk_fp8_f32(np0, np1, 0,  false);
  pw0          = __builtin_amdgcn_cvt_pk_fp8_f32(np2, np3, pw0, true);
  uint32_t pw1 = __builtin_amdgcn_cvt_pk_fp8_f32(np4, np5, 0,  false);
  pw1          = __builtin_amdgcn_cvt_pk_fp8_f32(np6, np7, pw1, true);

  ((uint2*)a8)[(size_t)r * 64 + lane] = make_uint2(aw0, aw1);
  ((uint2*)p8)[(size_t)r * 64 + lane] = make_uint2(pw0, pw1);

  if (lane == 0) {
    cos_ap[r] = dp / fmaxf(na * np, 1e-8f);
    minenc[r] = 0xFFFFFFFFu;   // +inf in monotone encoding
  }
  if (blockIdx.x == 0 && threadIdx.x == 0) *donecnt = 0u;
}

// ---------------------------------------------------------------------------
// global -> LDS direct load, 16B per lane (dest = wave-uniform base + lane*16).
// ---------------------------------------------------------------------------
__device__ __forceinline__ void load16_to_lds(const void* g, void* l) {
  __builtin_amdgcn_global_load_lds(
      (__attribute__((address_space(1))) uint32_t*)(uintptr_t)(g),
      (__attribute__((address_space(3))) uint32_t*)(uintptr_t)(l),
      16, 0, 0);
}

// ---------------------------------------------------------------------------
// Kernel 2: 128x128 fp8 MX-MFMA (16x16x128, scale=1.0) tile of A_n * P_n^T,
// fused diag-masked row-min -> device atomicMin, fused last-block finalize.
//
// R5 post-mortem: 32x32 restructure quadrupled stall (64 B glds segments +
// 8 barriers) -- reverted to R2/R4-proven shape (128 B-line segments, BK=128,
// 4 iters, 2 barriers). R6 lever: occupancy. Single LDS buffer (33 KB) +
// launch_bounds(256,3) -> 3 blocks/CU (12 waves) vs the 2 blocks (8 waves)
// every prior round ran at; independent block phases cover barrier drains.
// bfr loaded one-at-a-time inside the nf loop to keep live regs ~130 < 170.
// ---------------------------------------------------------------------------
__global__ __launch_bounds__(256, 3) void simmin_kernel(
    const uint8_t* __restrict__ a8, const uint8_t* __restrict__ p8,
    uint32_t* __restrict__ minenc, const float* __restrict__ cos_ap,
    uint32_t* __restrict__ donecnt, float* __restrict__ out)
{
  __shared__ __attribute__((aligned(16))) uint8_t Alds[128 * 128];
  __shared__ __attribute__((aligned(16))) uint8_t Plds[128 * 128];
  __shared__ float redmin[256];
  __shared__ int   isLast;

  const int tid  = threadIdx.x;
  const int lane = tid & 63;
  const int wave = tid >> 6;
  const int waveM = wave >> 1, waveN = wave & 1;
  const int quad = lane >> 4;
  const int l15  = lane & 15;

  // XCD super-tile swizzle: xcd=bid&7 keeps its 8 A-rowTiles L2-resident
  const int bid = blockIdx.x;
  const int blockRow = (bid & 7) * 8 + ((bid >> 3) & 7);
  const int blockCol = bid >> 6;

  f32x4 acc[4][4];
  const f32x4 zero = {0.f, 0.f, 0.f, 0.f};
#pragma unroll
  for (int i = 0; i < 4; i++)
#pragma unroll
    for (int j = 0; j < 4; j++) acc[i][j] = zero;

  // staging: chunk = 8 rows x 128 B (full cache lines); lane i: row = i/8,
  // XOR-swizzled k-slot fetched pre-swizzled on the global side.
  const int srow = lane >> 3;
  const int sk   = (lane & 7) ^ srow;
  const uint8_t* aBase = a8 + (size_t)(blockRow * 128) * D_DIM;
  const uint8_t* pBase = p8 + (size_t)(blockCol * 128) * D_DIM;

  for (int k0 = 0; k0 < D_DIM; k0 += 128) {
#pragma unroll
    for (int c = 0; c < 4; c++) {
      const int chunk = wave * 4 + c;       // 0..15
      const size_t goff = (size_t)(chunk * 8 + srow) * D_DIM + k0 + sk * 16;
      load16_to_lds(aBase + goff, &Alds[chunk * 1024]);
      load16_to_lds(pBase + goff, &Plds[chunk * 1024]);
    }
    __syncthreads();                        // drain glds -> LDS valid

    i32x8 af[4];
#pragma unroll
    for (int mf = 0; mf < 4; mf++) {
      const int r = waveM * 64 + mf * 16 + l15;
      const int rx = r & 7;
      const int4 lo = *(const int4*)&Alds[r * 128 + (((quad * 2 + 0) ^ rx) * 16)];
      const int4 hi = *(const int4*)&Alds[r * 128 + (((quad * 2 + 1) ^ rx) * 16)];
      af[mf] = (i32x8){lo.x, lo.y, lo.z, lo.w, hi.x, hi.y, hi.z, hi.w};
    }
#pragma unroll
    for (int nf = 0; nf < 4; nf++) {        // bfr one-at-a-time: low reg count
      const int r = waveN * 64 + nf * 16 + l15;
      const int rx = r & 7;
      const int4 lo = *(const int4*)&Plds[r * 128 + (((quad * 2 + 0) ^ rx) * 16)];
      const int4 hi = *(const int4*)&Plds[r * 128 + (((quad * 2 + 1) ^ rx) * 16)];
      const i32x8 bfr = (i32x8){lo.x, lo.y, lo.z, lo.w, hi.x, hi.y, hi.z, hi.w};
#pragma unroll
      for (int mf = 0; mf < 4; mf++)
        acc[mf][nf] = __builtin_amdgcn_mfma_scale_f32_16x16x128_f8f6f4(
            af[mf], bfr, acc[mf][nf],
            0, 0,                 // cbsz=fp8(e4m3) A, blgp=fp8(e4m3) B
            0, 0x7F7F7F7F,        // scale A (2^0)
            0, 0x7F7F7F7F);       // scale B (2^0)
    }
    __syncthreads();                        // all reads done before next stage
  }

  // ---- fused epilogue: per-row min over this block's 128 cols, diag masked
  // C/D layout (verified): col = l15, row = quad*4 + reg
  const int rowTileBase = blockRow * 128 + waveM * 64;
  const int colTileBase = blockCol * 128 + waveN * 64;

  float rm[4][4];
#pragma unroll
  for (int mf = 0; mf < 4; mf++)
#pragma unroll
    for (int r = 0; r < 4; r++) rm[mf][r] = 3.0e38f;

#pragma unroll
  for (int mf = 0; mf < 4; mf++) {
#pragma unroll
    for (int nf = 0; nf < 4; nf++) {
      const int col = colTileBase + nf * 16 + l15;
#pragma unroll
      for (int r = 0; r < 4; r++) {
        const int row = rowTileBase + mf * 16 + quad * 4 + r;
        const float v = acc[mf][nf][r];
        rm[mf][r] = (row == col) ? rm[mf][r] : fminf(rm[mf][r], v);
      }
    }
  }
#pragma unroll
  for (int d = 1; d < 16; d <<= 1)
#pragma unroll
    for (int mf = 0; mf < 4; mf++)
#pragma unroll
      for (int r = 0; r < 4; r++)
        rm[mf][r] = fminf(rm[mf][r], __shfl_xor(rm[mf][r], d));

  if (l15 == 0) {
#pragma unroll
    for (int mf = 0; mf < 4; mf++)
#pragma unroll
      for (int r = 0; r < 4; r++)
        redmin[waveN * 128 + waveM * 64 + mf * 16 + quad * 4 + r] = rm[mf][r];
  }
  __syncthreads();

  if (tid < 128) {
    const float m = fminf(redmin[tid], redmin[128 + tid]);
    atomicMin(&minenc[blockRow * 128 + tid], enc_f32(m));  // device-scope
  }

  // ---- fused finalize: last block to arrive reduces the loss
  __threadfence();
  if (tid == 0) {
    const uint32_t old = atomicAdd(donecnt, 1u);
    isLast = (old == (uint32_t)(GRID_SIMMIN - 1));
  }
  __syncthreads();
  if (isLast) {
    float sum = 0.0f;
    for (int r = tid; r < B_ROWS; r += 256) {
      const uint32_t e = atomicOr(&minenc[r], 0u);  // coherent atomic read
      sum += fmaxf(0.0f, 1.0f + cos_ap[r] - dec_f32(e));
    }
#pragma unroll
    for (int d = 1; d < 64; d <<= 1) sum += __shfl_xor(sum, d);
    if ((tid & 63) == 0) redmin[tid >> 6] = sum;
    __syncthreads();
    if (tid == 0)
      out[0] = (redmin[0] + redmin[1] + redmin[2] + redmin[3])
               * (1.0f / (float)B_ROWS);
  }
}

// ---------------------------------------------------------------------------
extern "C" void kernel_launch(void* const* d_in, const int* in_sizes, int n_in,
                              void* d_out, int out_size, void* d_ws, size_t ws_size,
                              hipStream_t stream) {
  const float* anchor   = (const float*)d_in[0];
  const float* positive = (const float*)d_in[1];

  char* ws = (char*)d_ws;
  uint32_t* a8      = (uint32_t*)(ws);                                // 4 MB
  uint32_t* p8      = (uint32_t*)(ws + (4ull << 20));                 // 4 MB
  float*    cos_ap  = (float*)(ws + (8ull << 20));                    // 32 KB
  uint32_t* minenc  = (uint32_t*)(ws + (8ull << 20) + (32ull << 10)); // 32 KB
  uint32_t* donecnt = (uint32_t*)(ws + (8ull << 20) + (64ull << 10));
  float*    out = (float*)d_out;

  norm_kernel<<<B_ROWS / 4, 256, 0, stream>>>(anchor, positive, a8, p8,
                                              cos_ap, minenc, donecnt);
  simmin_kernel<<<GRID_SIMMIN, 256, 0, stream>>>((const uint8_t*)a8,
                                                 (const uint8_t*)p8, minenc,
                                                 cos_ap, donecnt, out);
}

// Round 7
// 144.112 us; speedup vs baseline: 2.4110x; 2.4110x over previous
//
#include <hip/hip_runtime.h>
#include <stdint.h>

typedef int   i32x8 __attribute__((ext_vector_type(8)));
typedef float f32x4 __attribute__((ext_vector_type(4)));

#define B_ROWS 8192
#define D_DIM  512

// monotone float<->uint encoding: enc order == float order (uint atomicMin
// == float min). f>=0: set sign bit; f<0: bitwise NOT.
__device__ __forceinline__ uint32_t enc_f32(float f) {
  uint32_t s = __float_as_uint(f);
  return (s & 0x80000000u) ? ~s : (s | 0x80000000u);
}
__device__ __forceinline__ float dec_f32(uint32_t e) {
  uint32_t s = (e & 0x80000000u) ? (e ^ 0x80000000u) : ~e;
  return __uint_as_float(s);
}

// ---------------------------------------------------------------------------
// Kernel 1: per-row normalize (fp32 -> fp8 e4m3) + cos(anchor, positive).
// Wave per row. Inits minenc[r] = +inf encoding (replaces a memset node).
// ---------------------------------------------------------------------------
__global__ __launch_bounds__(256) void norm_kernel(
    const float* __restrict__ anchor, const float* __restrict__ positive,
    uint32_t* __restrict__ a8, uint32_t* __restrict__ p8,
    float* __restrict__ cos_ap, uint32_t* __restrict__ minenc)
{
  const int wave = threadIdx.x >> 6, lane = threadIdx.x & 63;
  const int r = blockIdx.x * 4 + wave;

  const float4* av = (const float4*)(anchor   + (size_t)r * D_DIM) + lane * 2;
  const float4* pv = (const float4*)(positive + (size_t)r * D_DIM) + lane * 2;
  float4 a0 = av[0], a1 = av[1];
  float4 p0 = pv[0], p1 = pv[1];

  float sa = a0.x*a0.x + a0.y*a0.y + a0.z*a0.z + a0.w*a0.w
           + a1.x*a1.x + a1.y*a1.y + a1.z*a1.z + a1.w*a1.w;
  float sp = p0.x*p0.x + p0.y*p0.y + p0.z*p0.z + p0.w*p0.w
           + p1.x*p1.x + p1.y*p1.y + p1.z*p1.z + p1.w*p1.w;
  float dp = a0.x*p0.x + a0.y*p0.y + a0.z*p0.z + a0.w*p0.w
           + a1.x*p1.x + a1.y*p1.y + a1.z*p1.z + a1.w*p1.w;

#pragma unroll
  for (int d = 1; d < 64; d <<= 1) {
    sa += __shfl_xor(sa, d);
    sp += __shfl_xor(sp, d);
    dp += __shfl_xor(dp, d);
  }

  const float na = sqrtf(sa), np = sqrtf(sp);
  const float ia = 1.0f / na, ip = 1.0f / np;

  float na0 = a0.x*ia, na1 = a0.y*ia, na2 = a0.z*ia, na3 = a0.w*ia;
  float na4 = a1.x*ia, na5 = a1.y*ia, na6 = a1.z*ia, na7 = a1.w*ia;
  float np0 = p0.x*ip, np1 = p0.y*ip, np2 = p0.z*ip, np3 = p0.w*ip;
  float np4 = p1.x*ip, np5 = p1.y*ip, np6 = p1.z*ip, np7 = p1.w*ip;

  uint32_t aw0 = __builtin_amdgcn_cvt_pk_fp8_f32(na0, na1, 0,  false);
  aw0          = __builtin_amdgcn_cvt_pk_fp8_f32(na2, na3, aw0, true);
  uint32_t aw1 = __builtin_amdgcn_cvt_pk_fp8_f32(na4, na5, 0,  false);
  aw1          = __builtin_amdgcn_cvt_pk_fp8_f32(na6, na7, aw1, true);
  uint32_t pw0 = __builtin_amdgcn_cvt_pk_fp8_f32(np0, np1, 0,  false);
  pw0          = __builtin_amdgcn_cvt_pk_fp8_f32(np2, np3, pw0, true);
  uint32_t pw1 = __builtin_amdgcn_cvt_pk_fp8_f32(np4, np5, 0,  false);
  pw1          = __builtin_amdgcn_cvt_pk_fp8_f32(np6, np7, pw1, true);

  ((uint2*)a8)[(size_t)r * 64 + lane] = make_uint2(aw0, aw1);
  ((uint2*)p8)[(size_t)r * 64 + lane] = make_uint2(pw0, pw1);

  if (lane == 0) {
    cos_ap[r] = dp / fmaxf(na * np, 1e-8f);
    minenc[r] = 0xFFFFFFFFu;   // +inf in monotone encoding
  }
}

// ---------------------------------------------------------------------------
// global -> LDS direct load, 16B per lane (dest = wave-uniform base + lane*16).
// ---------------------------------------------------------------------------
__device__ __forceinline__ void load16_to_lds(const void* g, void* l) {
  __builtin_amdgcn_global_load_lds(
      (__attribute__((address_space(1))) uint32_t*)(uintptr_t)(g),
      (__attribute__((address_space(3))) uint32_t*)(uintptr_t)(l),
      16, 0, 0);
}

// ---------------------------------------------------------------------------
// Kernel 2: 128x128 fp8 MX-MFMA (16x16x128, scale=1.0) tile of A_n * P_n^T,
// fused diag-masked row-min -> device atomicMin.
//
// R7: R4-proven structure (dbuf P, 1 barrier/iter, XCD swizzle, NO
// threadfence -- R5/R6 showed per-block device fences cause an L2-invalidate
// storm, 4-5x regression). New lever: A bypasses LDS entirely -- fragments
// load straight from global (L2-resident rows via swizzle) with a one-iter
// register pipeline. LDS pipe demand drops ~2500 -> ~1280 cyc/CU/iter
// (~= matrix pipe ~1100): P-only staging (2x16 KB), half the ds_reads,
// half the conflicts, half the glds-writes.
// ---------------------------------------------------------------------------
__global__ __launch_bounds__(256, 2) void simmin_kernel(
    const uint8_t* __restrict__ a8, const uint8_t* __restrict__ p8,
    uint32_t* __restrict__ minenc)
{
  __shared__ __attribute__((aligned(16))) uint8_t Plds[2][128 * 128];
  __shared__ float redmin[256];

  const int tid  = threadIdx.x;
  const int lane = tid & 63;
  const int wave = tid >> 6;
  const int waveM = wave >> 1, waveN = wave & 1;
  const int quad = lane >> 4;
  const int l15  = lane & 15;

  // XCD super-tile swizzle: xcd=bid&7 keeps its 8 A-rowTiles L2-resident
  const int bid = blockIdx.x;
  const int blockRow = (bid & 7) * 8 + ((bid >> 3) & 7);
  const int blockCol = bid >> 6;

  f32x4 acc[4][4];
  const f32x4 zero = {0.f, 0.f, 0.f, 0.f};
#pragma unroll
  for (int i = 0; i < 4; i++)
#pragma unroll
    for (int j = 0; j < 4; j++) acc[i][j] = zero;

  // ---- P staging: chunk = 8 rows x 128 B (full cache lines); lane i:
  // row = i/8, XOR-swizzled k-slot fetched pre-swizzled on the global side.
  const int srow = lane >> 3;
  const int sk   = (lane & 7) ^ srow;
  const uint8_t* pBase = p8 + (size_t)(blockCol * 128) * D_DIM;

  auto stageP = [&](int k0, int buf) {
#pragma unroll
    for (int c = 0; c < 4; c++) {
      const int chunk = wave * 4 + c;       // 0..15
      const size_t goff = (size_t)(chunk * 8 + srow) * D_DIM + k0 + sk * 16;
      load16_to_lds(pBase + goff, &Plds[buf][chunk * 1024]);
    }
  };

  // ---- A fragments direct from global: lane's row pointer per m-frag,
  // k-window = k0 + quad*32 (+16). Same lane->element mapping as the LDS
  // path, just sourced from L2.
  const uint8_t* aRow[4];
#pragma unroll
  for (int mf = 0; mf < 4; mf++)
    aRow[mf] = a8 + (size_t)(blockRow * 128 + waveM * 64 + mf * 16 + l15) * D_DIM
               + quad * 32;

  auto loadA = [&](int k0, i32x8* dst) {
#pragma unroll
    for (int mf = 0; mf < 4; mf++) {
      const int4 lo = *(const int4*)(aRow[mf] + k0);
      const int4 hi = *(const int4*)(aRow[mf] + k0 + 16);
      dst[mf] = (i32x8){lo.x, lo.y, lo.z, lo.w, hi.x, hi.y, hi.z, hi.w};
    }
  };

  i32x8 af[2][4];          // register double-buffer for A (one iter ahead)
  stageP(0, 0);
  loadA(0, af[0]);

#pragma unroll
  for (int k = 0; k < 4; k++) {
    __syncthreads();                        // P staged into buf[k&1]
    const int buf = k & 1;

    i32x8 bfr[4];
#pragma unroll
    for (int nf = 0; nf < 4; nf++) {
      const int r = waveN * 64 + nf * 16 + l15;
      const int rx = r & 7;
      const int4 lo = *(const int4*)&Plds[buf][r * 128 + (((quad * 2 + 0) ^ rx) * 16)];
      const int4 hi = *(const int4*)&Plds[buf][r * 128 + (((quad * 2 + 1) ^ rx) * 16)];
      bfr[nf] = (i32x8){lo.x, lo.y, lo.z, lo.w, hi.x, hi.y, hi.z, hi.w};
    }

    if (k < 3) {
      stageP((k + 1) * 128, (k + 1) & 1);   // prefetch next P tile -> LDS
      loadA((k + 1) * 128, af[(k + 1) & 1]); // prefetch next A frags -> regs
    }

#pragma unroll
    for (int mf = 0; mf < 4; mf++)
#pragma unroll
      for (int nf = 0; nf < 4; nf++)
        acc[mf][nf] = __builtin_amdgcn_mfma_scale_f32_16x16x128_f8f6f4(
            af[buf][mf], bfr[nf], acc[mf][nf],
            0, 0,                 // cbsz=fp8(e4m3) A, blgp=fp8(e4m3) B
            0, 0x7F7F7F7F,        // scale A (2^0)
            0, 0x7F7F7F7F);       // scale B (2^0)
  }

  // ---- fused epilogue: per-row min over this block's 128 cols, diag masked
  // C/D layout (verified): col = l15, row = quad*4 + reg
  const int rowTileBase = blockRow * 128 + waveM * 64;
  const int colTileBase = blockCol * 128 + waveN * 64;

  float rm[4][4];
#pragma unroll
  for (int mf = 0; mf < 4; mf++)
#pragma unroll
    for (int r = 0; r < 4; r++) rm[mf][r] = 3.0e38f;

#pragma unroll
  for (int mf = 0; mf < 4; mf++) {
#pragma unroll
    for (int nf = 0; nf < 4; nf++) {
      const int col = colTileBase + nf * 16 + l15;
#pragma unroll
      for (int r = 0; r < 4; r++) {
        const int row = rowTileBase + mf * 16 + quad * 4 + r;
        const float v = acc[mf][nf][r];
        rm[mf][r] = (row == col) ? rm[mf][r] : fminf(rm[mf][r], v);
      }
    }
  }
#pragma unroll
  for (int d = 1; d < 16; d <<= 1)
#pragma unroll
    for (int mf = 0; mf < 4; mf++)
#pragma unroll
      for (int r = 0; r < 4; r++)
        rm[mf][r] = fminf(rm[mf][r], __shfl_xor(rm[mf][r], d));

  if (l15 == 0) {
#pragma unroll
    for (int mf = 0; mf < 4; mf++)
#pragma unroll
      for (int r = 0; r < 4; r++)
        redmin[waveN * 128 + waveM * 64 + mf * 16 + quad * 4 + r] = rm[mf][r];
  }
  __syncthreads();

  if (tid < 128) {
    const float m = fminf(redmin[tid], redmin[128 + tid]);
    atomicMin(&minenc[blockRow * 128 + tid], enc_f32(m));  // device-scope
  }
}

// ---------------------------------------------------------------------------
// Kernel 3: single block (1024 thr) — decode row-mins, loss, mean, store.
// ---------------------------------------------------------------------------
__global__ __launch_bounds__(1024) void finalize_kernel(
    const uint32_t* __restrict__ minenc, const float* __restrict__ cos_ap,
    float* __restrict__ out)
{
  float sum = 0.0f;
#pragma unroll
  for (int r = threadIdx.x; r < B_ROWS; r += 1024)
    sum += fmaxf(0.0f, 1.0f + cos_ap[r] - dec_f32(minenc[r]));

#pragma unroll
  for (int d = 1; d < 64; d <<= 1) sum += __shfl_xor(sum, d);
  __shared__ float s[16];
  if ((threadIdx.x & 63) == 0) s[threadIdx.x >> 6] = sum;
  __syncthreads();
  if (threadIdx.x < 64) {
    float t = (threadIdx.x < 16) ? s[threadIdx.x] : 0.0f;
#pragma unroll
    for (int d = 1; d < 16; d <<= 1) t += __shfl_xor(t, d);
    if (threadIdx.x == 0) out[0] = t * (1.0f / (float)B_ROWS);
  }
}

// ---------------------------------------------------------------------------
extern "C" void kernel_launch(void* const* d_in, const int* in_sizes, int n_in,
                              void* d_out, int out_size, void* d_ws, size_t ws_size,
                              hipStream_t stream) {
  const float* anchor   = (const float*)d_in[0];
  const float* positive = (const float*)d_in[1];

  char* ws = (char*)d_ws;
  uint32_t* a8     = (uint32_t*)(ws);                                // 4 MB
  uint32_t* p8     = (uint32_t*)(ws + (4ull << 20));                 // 4 MB
  float*    cos_ap = (float*)(ws + (8ull << 20));                    // 32 KB
  uint32_t* minenc = (uint32_t*)(ws + (8ull << 20) + (32ull << 10)); // 32 KB
  float*    out = (float*)d_out;

  norm_kernel<<<B_ROWS / 4, 256, 0, stream>>>(anchor, positive, a8, p8,
                                              cos_ap, minenc);
  simmin_kernel<<<4096, 256, 0, stream>>>((const uint8_t*)a8,
                                          (const uint8_t*)p8, minenc);
  finalize_kernel<<<1, 1024, 0, stream>>>(minenc, cos_ap, out);
}

// Round 8
// 132.243 us; speedup vs baseline: 2.6274x; 1.0898x over previous
//
#include <hip/hip_runtime.h>
#include <stdint.h>

typedef int   i32x8  __attribute__((ext_vector_type(8)));
typedef float f32x16 __attribute__((ext_vector_type(16)));

#define B_ROWS 8192
#define D_DIM  512

// monotone float<->uint encoding: enc order == float order (uint atomicMin
// == float min). f>=0: set sign bit; f<0: bitwise NOT.
__device__ __forceinline__ uint32_t enc_f32(float f) {
  uint32_t s = __float_as_uint(f);
  return (s & 0x80000000u) ? ~s : (s | 0x80000000u);
}
__device__ __forceinline__ float dec_f32(uint32_t e) {
  uint32_t s = (e & 0x80000000u) ? (e ^ 0x80000000u) : ~e;
  return __uint_as_float(s);
}

// ---------------------------------------------------------------------------
// Transposed fp8 layout ("frag-ready"): tile(rowBlk, kBlk) = 32 rows x 64 K
// = 2048 B at offset (rowBlk*8 + kBlk)*2048. Within a tile, the byte for
// (row = rowBlk*32 + r31, k = kBlk*64 + h*32 + j*16 + b), b<16, is at
// j*1024 + (h*32 + r31)*16 + b.  =>  a wave's frag load for (rowBlk,kBlk)
// is two fully-coalesced dwordx4 loads at {base + lane*16, +1024}
// (lane = h*32 + r31), matching the R5-hardware-validated 32x32x64 A/B
// operand mapping: row = lane&31, k = (lane>>5)*32 + byte.
// ---------------------------------------------------------------------------

// ---------------------------------------------------------------------------
// Kernel 1: per-row normalize (fp32 -> fp8 e4m3) + cos(anchor, positive),
// storing a8t/p8t in the transposed frag-ready layout. Wave per row: after
// packing, lane L holds bytes [L*8, L*8+8); 16-B chunk c gathers lanes
// 2c, 2c+1 via shuffles; lanes 0-31 store A-chunks, lanes 32-63 P-chunks.
// Also inits minenc[r] = +inf encoding.
// ---------------------------------------------------------------------------
__global__ __launch_bounds__(256) void norm_kernel(
    const float* __restrict__ anchor, const float* __restrict__ positive,
    uint8_t* __restrict__ a8t, uint8_t* __restrict__ p8t,
    float* __restrict__ cos_ap, uint32_t* __restrict__ minenc)
{
  const int wave = threadIdx.x >> 6, lane = threadIdx.x & 63;
  const int r = blockIdx.x * 4 + wave;

  const float4* av = (const float4*)(anchor   + (size_t)r * D_DIM) + lane * 2;
  const float4* pv = (const float4*)(positive + (size_t)r * D_DIM) + lane * 2;
  float4 a0 = av[0], a1 = av[1];
  float4 p0 = pv[0], p1 = pv[1];

  float sa = a0.x*a0.x + a0.y*a0.y + a0.z*a0.z + a0.w*a0.w
           + a1.x*a1.x + a1.y*a1.y + a1.z*a1.z + a1.w*a1.w;
  float sp = p0.x*p0.x + p0.y*p0.y + p0.z*p0.z + p0.w*p0.w
           + p1.x*p1.x + p1.y*p1.y + p1.z*p1.z + p1.w*p1.w;
  float dp = a0.x*p0.x + a0.y*p0.y + a0.z*p0.z + a0.w*p0.w
           + a1.x*p1.x + a1.y*p1.y + a1.z*p1.z + a1.w*p1.w;

#pragma unroll
  for (int d = 1; d < 64; d <<= 1) {
    sa += __shfl_xor(sa, d);
    sp += __shfl_xor(sp, d);
    dp += __shfl_xor(dp, d);
  }

  const float na = sqrtf(sa), np = sqrtf(sp);
  const float ia = 1.0f / na, ip = 1.0f / np;

  float na0 = a0.x*ia, na1 = a0.y*ia, na2 = a0.z*ia, na3 = a0.w*ia;
  float na4 = a1.x*ia, na5 = a1.y*ia, na6 = a1.z*ia, na7 = a1.w*ia;
  float np0 = p0.x*ip, np1 = p0.y*ip, np2 = p0.z*ip, np3 = p0.w*ip;
  float np4 = p1.x*ip, np5 = p1.y*ip, np6 = p1.z*ip, np7 = p1.w*ip;

  uint32_t aw0 = __builtin_amdgcn_cvt_pk_fp8_f32(na0, na1, 0,  false);
  aw0          = __builtin_amdgcn_cvt_pk_fp8_f32(na2, na3, aw0, true);
  uint32_t aw1 = __builtin_amdgcn_cvt_pk_fp8_f32(na4, na5, 0,  false);
  aw1          = __builtin_amdgcn_cvt_pk_fp8_f32(na6, na7, aw1, true);
  uint32_t pw0 = __builtin_amdgcn_cvt_pk_fp8_f32(np0, np1, 0,  false);
  pw0          = __builtin_amdgcn_cvt_pk_fp8_f32(np2, np3, pw0, true);
  uint32_t pw1 = __builtin_amdgcn_cvt_pk_fp8_f32(np4, np5, 0,  false);
  pw1          = __builtin_amdgcn_cvt_pk_fp8_f32(np6, np7, pw1, true);

  // gather chunk c = lane&31: bytes [c*16, c*16+16) from lanes 2c, 2c+1
  const int c = lane & 31;
  const uint32_t A0 = __shfl(aw0, c*2),   A1 = __shfl(aw1, c*2);
  const uint32_t A2 = __shfl(aw0, c*2+1), A3 = __shfl(aw1, c*2+1);
  const uint32_t P0 = __shfl(pw0, c*2),   P1 = __shfl(pw1, c*2);
  const uint32_t P2 = __shfl(pw0, c*2+1), P3 = __shfl(pw1, c*2+1);

  const int kBlk = c >> 2, h = (c >> 1) & 1, j = c & 1;
  const size_t off = ((size_t)((r >> 5) * 8 + kBlk)) * 2048 + j * 1024
                   + ((h * 32 + (r & 31)) * 16);
  if (lane < 32) *(uint4*)(a8t + off) = make_uint4(A0, A1, A2, A3);
  else           *(uint4*)(p8t + off) = make_uint4(P0, P1, P2, P3);

  if (lane == 0) {
    cos_ap[r] = dp / fmaxf(na * np, 1e-8f);
    minenc[r] = 0xFFFFFFFFu;   // +inf in monotone encoding
  }
}

// ---------------------------------------------------------------------------
// Kernel 2: sim = A_n * P_n^T via 32x32x64 MX-fp8 MFMA (scale=1.0), fused
// diag-masked row-min -> device atomicMin. BARRIER-FREE, LDS-FREE K-loop:
// fragments load coalesced straight from L2 (pre-transposed layout),
// register-double-buffered one kBlk ahead. R7 post-mortem: the staged+
// barriered loop fully serializes LDS and MFMA pipes (2137 ~= 1536+554
// cyc/block-iter); removing both lets vmem and matrix pipes overlap.
// Block 128m x 256n, 4 waves each 128m x 64n (4mf x 2nf of 32x32),
// 8 kBlks of K=64. XCD swizzle keeps each XCD's A slice (512 KB) L2-hot.
// NO __threadfence (R5/R6: per-block device fences = L2-invalidate storm).
// ---------------------------------------------------------------------------
__global__ __launch_bounds__(256, 2) void simmin_kernel(
    const uint8_t* __restrict__ a8t, const uint8_t* __restrict__ p8t,
    uint32_t* __restrict__ minenc)
{
  __shared__ float redmin[4][128];

  const int tid  = threadIdx.x;
  const int lane = tid & 63;
  const int wave = tid >> 6;        // wave owns cols [wave*64, wave*64+64)
  const int half = lane >> 5;
  const int r31  = lane & 31;

  const int bid = blockIdx.x;
  const int blockRow = (bid & 7) * 8 + ((bid >> 3) & 7);  // 0..63
  const int blockCol = bid >> 6;                          // 0..31

  f32x16 acc[4][2];
#pragma unroll
  for (int i = 0; i < 4; i++)
#pragma unroll
    for (int j = 0; j < 2; j++)
#pragma unroll
      for (int e = 0; e < 16; e++) acc[i][j][e] = 0.f;

  // frag-tile base pointers (lane offset baked in)
  const uint8_t* aT[4];
#pragma unroll
  for (int mf = 0; mf < 4; mf++)
    aT[mf] = a8t + ((size_t)(blockRow * 4 + mf)) * (8 * 2048) + lane * 16;
  const uint8_t* pT[2];
#pragma unroll
  for (int nf = 0; nf < 2; nf++)
    pT[nf] = p8t + ((size_t)(blockCol * 8 + wave * 2 + nf)) * (8 * 2048) + lane * 16;

  i32x8 af[2][4], bf[2][2];

  auto loadA = [&](int kb, int buf) {
#pragma unroll
    for (int mf = 0; mf < 4; mf++) {
      const uint8_t* t = aT[mf] + kb * 2048;
      const int4 lo = *(const int4*)t;
      const int4 hi = *(const int4*)(t + 1024);
      af[buf][mf] = (i32x8){lo.x, lo.y, lo.z, lo.w, hi.x, hi.y, hi.z, hi.w};
    }
  };
  auto loadB = [&](int kb, int buf) {
#pragma unroll
    for (int nf = 0; nf < 2; nf++) {
      const uint8_t* t = pT[nf] + kb * 2048;
      const int4 lo = *(const int4*)t;
      const int4 hi = *(const int4*)(t + 1024);
      bf[buf][nf] = (i32x8){lo.x, lo.y, lo.z, lo.w, hi.x, hi.y, hi.z, hi.w};
    }
  };

  loadA(0, 0);
  loadB(0, 0);

#pragma unroll
  for (int kb = 0; kb < 8; kb++) {
    const int cur = kb & 1, nxt = cur ^ 1;
    if (kb < 7) { loadA(kb + 1, nxt); loadB(kb + 1, nxt); }  // prefetch

#pragma unroll
    for (int mf = 0; mf < 4; mf++)
#pragma unroll
      for (int nf = 0; nf < 2; nf++)
        acc[mf][nf] = __builtin_amdgcn_mfma_scale_f32_32x32x64_f8f6f4(
            af[cur][mf], bf[cur][nf], acc[mf][nf],
            0, 0,                 // cbsz=fp8(e4m3) A, blgp=fp8(e4m3) B
            0, 0x7F7F7F7F,        // scale A (2^0)
            0, 0x7F7F7F7F);       // scale B (2^0)
  }

  // ---- epilogue (R5-hardware-validated layout): diag-masked row-min
  // C/D 32x32: row = (g&3) + 8*(g>>2) + 4*half, col = lane&31
  float rm[4][16];
#pragma unroll
  for (int mf = 0; mf < 4; mf++)
#pragma unroll
    for (int g = 0; g < 16; g++) rm[mf][g] = 3.0e38f;

#pragma unroll
  for (int mf = 0; mf < 4; mf++) {
#pragma unroll
    for (int nf = 0; nf < 2; nf++) {
      const int col = blockCol * 256 + wave * 64 + nf * 32 + r31;
#pragma unroll
      for (int g = 0; g < 16; g++) {
        const int row = blockRow * 128 + mf * 32 + (g & 3) + 8 * (g >> 2) + 4 * half;
        const float v = acc[mf][nf][g];
        rm[mf][g] = (row == col) ? rm[mf][g] : fminf(rm[mf][g], v);
      }
    }
  }
  // butterfly min over the 32 col-lanes (bit5 = half stays fixed)
#pragma unroll
  for (int d = 1; d < 32; d <<= 1)
#pragma unroll
    for (int mf = 0; mf < 4; mf++)
#pragma unroll
      for (int g = 0; g < 16; g++)
        rm[mf][g] = fminf(rm[mf][g], __shfl_xor(rm[mf][g], d));

  if (r31 == 0) {
#pragma unroll
    for (int mf = 0; mf < 4; mf++)
#pragma unroll
      for (int g = 0; g < 16; g++)
        redmin[wave][mf * 32 + (g & 3) + 8 * (g >> 2) + 4 * half] = rm[mf][g];
  }
  __syncthreads();

  if (tid < 128) {
    const float m = fminf(fminf(redmin[0][tid], redmin[1][tid]),
                          fminf(redmin[2][tid], redmin[3][tid]));
    atomicMin(&minenc[blockRow * 128 + tid], enc_f32(m));  // device-scope
  }
}

// ---------------------------------------------------------------------------
// Kernel 3: single block (1024 thr) — decode row-mins, loss, mean, store.
// ---------------------------------------------------------------------------
__global__ __launch_bounds__(1024) void finalize_kernel(
    const uint32_t* __restrict__ minenc, const float* __restrict__ cos_ap,
    float* __restrict__ out)
{
  float sum = 0.0f;
#pragma unroll
  for (int r = threadIdx.x; r < B_ROWS; r += 1024)
    sum += fmaxf(0.0f, 1.0f + cos_ap[r] - dec_f32(minenc[r]));

#pragma unroll
  for (int d = 1; d < 64; d <<= 1) sum += __shfl_xor(sum, d);
  __shared__ float s[16];
  if ((threadIdx.x & 63) == 0) s[threadIdx.x >> 6] = sum;
  __syncthreads();
  if (threadIdx.x < 64) {
    float t = (threadIdx.x < 16) ? s[threadIdx.x] : 0.0f;
#pragma unroll
    for (int d = 1; d < 16; d <<= 1) t += __shfl_xor(t, d);
    if (threadIdx.x == 0) out[0] = t * (1.0f / (float)B_ROWS);
  }
}

// ---------------------------------------------------------------------------
extern "C" void kernel_launch(void* const* d_in, const int* in_sizes, int n_in,
                              void* d_out, int out_size, void* d_ws, size_t ws_size,
                              hipStream_t stream) {
  const float* anchor   = (const float*)d_in[0];
  const float* positive = (const float*)d_in[1];

  char* ws = (char*)d_ws;
  uint8_t*  a8t    = (uint8_t*)(ws);                                // 4 MB
  uint8_t*  p8t    = (uint8_t*)(ws + (4ull << 20));                 // 4 MB
  float*    cos_ap = (float*)(ws + (8ull << 20));                   // 32 KB
  uint32_t* minenc = (uint32_t*)(ws + (8ull << 20) + (32ull << 10));// 32 KB
  float*    out = (float*)d_out;

  norm_kernel<<<B_ROWS / 4, 256, 0, stream>>>(anchor, positive, a8t, p8t,
                                              cos_ap, minenc);
  simmin_kernel<<<2048, 256, 0, stream>>>(a8t, p8t, minenc);
  finalize_kernel<<<1, 1024, 0, stream>>>(minenc, cos_ap, out);
}